// Round 2
// baseline (6127.827 us; speedup 1.0000x reference)
//
#include <hip/hip_runtime.h>

// Hyena QA forward: 12 depthwise long-conv residual layers + LN + 2-logit head.
// Global layout: channel-major tight rows x[c][0..4095], c = b*768 + d,
// signal at [0, 4095), element 4095 kept zero. SAME-conv halo zeros are
// materialized only in LDS. ws: 2 ping-pong buffers = 50.3 MB.

#define LSEQ   4095
#define DMODEL 768
#define KF     4095
#define CROW   4096      // per-channel row stride
#define NCH    1536      // B * D
#define BL     8190      // B * L

__device__ __forceinline__ int sw(int e) { return e + (e >> 5); }  // LDS bank swizzle

// ---------------- embed: x[c=(b,d)][t] = emb[ids[b,t],d] + pos[t,d] ----------
__global__ __launch_bounds__(256)
void embed_kernel(const int* __restrict__ ids, const float* __restrict__ emb,
                  const float* __restrict__ pos, float* __restrict__ xout)
{
    __shared__ float tile[32 * 65];        // [t_rel][d_rel], +1 pad
    const int d0 = blockIdx.x * 64;
    const int t0 = blockIdx.y * 32;
    const int b  = blockIdx.z;
    const int tid = threadIdx.x;

    {   // read phase: coalesced along d
        const int lane = tid & 63, row = tid >> 6;
        #pragma unroll
        for (int r = 0; r < 8; ++r) {
            int tr = row * 8 + r;                    // 0..31
            int t  = t0 + tr;
            if (t < LSEQ) {
                int id = ids[b * LSEQ + t];
                tile[tr * 65 + lane] =
                    emb[(size_t)id * DMODEL + d0 + lane] +
                    pos[(size_t)t  * DMODEL + d0 + lane];
            }
        }
    }
    __syncthreads();
    {   // write phase: coalesced along t (transposed)
        const int lt = tid & 31, drow = tid >> 5;
        #pragma unroll
        for (int r = 0; r < 8; ++r) {
            int dr = drow * 8 + r;                   // 0..63
            int t  = t0 + lt;
            if (t < LSEQ)
                xout[(size_t)(b * DMODEL + d0 + dr) * CROW + t] = tile[lt * 65 + dr];
        }
    }
}

// ---------------- one residual long-conv layer --------------------------------
// y[t] = sum_k w[k] * x_pad[t+k], x_pad[j] = x[j-2047] in-range else 0.
// LDS lx[j'] holds x at j' = 2048 + t; read index e = base+1+k0+o+kk.
// 128 threads, 32 outputs/thread, 64-reg ring window (unroll 4).
__global__ __launch_bounds__(128)
void conv_kernel(const float* __restrict__ xin, float* __restrict__ xout,
                 const float* __restrict__ w, const float* __restrict__ bias)
{
    __shared__ float lx[8448];   // swizzled x_pad[0..8191]
    __shared__ float lw[4224];   // filter (plain idx) / epilogue staging (swizzled)

    const int c   = blockIdx.x;          // channel 0..1535
    const int d   = c % DMODEL;
    const int tid = threadIdx.x;
    const size_t choff = (size_t)c * CROW;

    // issue global x loads early (hide latency under the LDS zero-fill)
    float4 xv[8];
    const float4* src = (const float4*)(xin + choff);
    #pragma unroll
    for (int r = 0; r < 8; ++r) xv[r] = src[tid + 128 * r];

    for (int i = tid; i < 8448; i += 128) lx[i] = 0.0f;
    __syncthreads();

    #pragma unroll
    for (int r = 0; r < 8; ++r) {
        int i = tid + 128 * r;           // float4 index
        int s = sw(2048 + 4 * i);        // (4i)%32 <= 28: quad shares swizzle block
        lx[s] = xv[r].x; lx[s + 1] = xv[r].y; lx[s + 2] = xv[r].z; lx[s + 3] = xv[r].w;
    }
    const float* wrow = w + (size_t)d * KF;
    for (int i = tid; i < KF; i += 128) lw[i] = wrow[i];
    if (tid == 0) lw[KF] = 0.0f;         // tap 4095 pad
    const float bv = bias[d];
    __syncthreads();

    float acc[32];
    #pragma unroll
    for (int o = 0; o < 32; ++o) acc[o] = 0.0f;

    float xw[64];                         // ring window, slot p = m & 63
    const int base = tid * 32;
    #pragma unroll
    for (int m = 0; m < 31; ++m) xw[m] = lx[sw(base + 1 + m)];

    #pragma unroll 1
    for (int kb = 0; kb < 256; kb += 4) {         // 4 phases/iter, ring phase = jj
        #pragma unroll
        for (int jj = 0; jj < 4; ++jj) {
            const int k0 = (kb + jj) * 16;
            #pragma unroll
            for (int i = 0; i < 16; ++i)          // refill m = k0+31 .. k0+46
                xw[(16 * jj + 31 + i) & 63] = lx[sw(base + 1 + k0 + 31 + i)];
            #pragma unroll
            for (int kk = 0; kk < 16; ++kk) {
                const float wv = lw[k0 + kk];     // broadcast read
                #pragma unroll
                for (int o = 0; o < 32; ++o)
                    acc[o] = fmaf(wv, xw[(16 * jj + o + kk) & 63], acc[o]);
            }
        }
    }

    // epilogue: residual + bias, stage through lw (reused) for coalesced store
    __syncthreads();                     // everyone done reading weights
    #pragma unroll
    for (int o = 0; o < 32; ++o) {
        int t = base + o;
        float v = (t < LSEQ) ? (lx[sw(2048 + t)] + acc[o] + bv) : 0.0f;
        lw[sw(t)] = v;                   // lanes stride-32 -> 2-way, free
    }
    __syncthreads();
    float4* dst = (float4*)(xout + choff);
    #pragma unroll
    for (int r = 0; r < 8; ++r) {
        int i = tid + 128 * r;           // float4 index
        int s = sw(4 * i);
        float4 v = { lw[s], lw[s + 1], lw[s + 2], lw[s + 3] };
        dst[i] = v;                      // coalesced 16B/lane
    }
}

// ---------------- fused LayerNorm + (D x 2) head ------------------------------
__global__ __launch_bounds__(256)
void head_kernel(const float* __restrict__ x, const float* __restrict__ g,
                 const float* __restrict__ bb, const float* __restrict__ qw,
                 const float* __restrict__ qb, float* __restrict__ out)
{
    const int b = blockIdx.y;
    const int t = blockIdx.x * 256 + threadIdx.x;
    const bool valid = t < LSEQ;
    const int tt = valid ? t : 0;

    float s1 = 0.f, s2 = 0.f, q0 = 0.f, q1 = 0.f;
    float G0 = 0.f, G1 = 0.f, C0 = 0.f, C1 = 0.f;
    const float* xb = x + (size_t)b * DMODEL * CROW + tt;
    for (int dd = 0; dd < DMODEL; ++dd) {
        float xv = xb[(size_t)dd * CROW];        // coalesced across threads
        float gd = g[dd], bd = bb[dd];
        float w0 = qw[2 * dd], w1 = qw[2 * dd + 1];
        s1 += xv;
        s2 = fmaf(xv, xv, s2);
        q0 = fmaf(xv, gd * w0, q0);
        q1 = fmaf(xv, gd * w1, q1);
        G0 = fmaf(gd, w0, G0); G1 = fmaf(gd, w1, G1);
        C0 = fmaf(bd, w0, C0); C1 = fmaf(bd, w1, C1);
    }
    float m   = s1 * (1.0f / 768.0f);
    float var = s2 * (1.0f / 768.0f) - m * m;
    float r   = rsqrtf(var + 1e-5f);
    float l0  = r * (q0 - m * G0) + C0 + qb[0];
    float l1  = r * (q1 - m * G1) + C1 + qb[1];
    if (valid) {
        out[(size_t)b * LSEQ + t] = l0;               // logits[...,0]
        out[BL + (size_t)b * LSEQ + t] = l1;          // logits[...,1]
    }
}

extern "C" void kernel_launch(void* const* d_in, const int* in_sizes, int n_in,
                              void* d_out, int out_size, void* d_ws, size_t ws_size,
                              hipStream_t stream)
{
    const int*   ids = (const int*)  d_in[0];
    const float* emb = (const float*)d_in[1];
    const float* pos = (const float*)d_in[2];
    const float* fw  = (const float*)d_in[3];
    const float* fb  = (const float*)d_in[4];
    const float* lg  = (const float*)d_in[5];
    const float* lb  = (const float*)d_in[6];
    const float* qw  = (const float*)d_in[7];
    const float* qb  = (const float*)d_in[8];
    float* out = (float*)d_out;

    const size_t needed = (size_t)2 * NCH * CROW * sizeof(float);   // 50.3 MB
    if (ws_size < needed) return;        // refuse to scribble outside ws

    float* bufA = (float*)d_ws;
    float* bufB = bufA + (size_t)NCH * CROW;
    // zero both buffers (element 4095 of each row must be 0; ws is re-poisoned)
    hipMemsetAsync(d_ws, 0, needed, stream);

    embed_kernel<<<dim3(12, 128, 2), 256, 0, stream>>>(ids, emb, pos, bufA);

    const float* cur = bufA;
    float*       nxt = bufB;
    for (int l = 0; l < 12; ++l) {
        conv_kernel<<<NCH, 128, 0, stream>>>(cur, nxt,
                                             fw + (size_t)l * DMODEL * KF,
                                             fb + (size_t)l * DMODEL);
        const float* tmp = nxt;
        nxt = (float*)cur;
        cur = tmp;
    }
    // after 12 swaps result is back in bufA
    head_kernel<<<dim3(16, 2), 256, 0, stream>>>(cur, lg, lb, qw, qb, out);
}

// Round 3
// 5607.577 us; speedup vs baseline: 1.0928x; 1.0928x over previous
//
#include <hip/hip_runtime.h>

// Hyena QA forward: 12 depthwise long-conv residual layers + LN + 2-logit head.
// Global layout: channel-major tight rows x[c][0..4095], c = b*768 + d,
// signal at [0,4095), element 4095 kept zero. Conv halos exist only in LDS.
// ws: 2 ping-pong buffers = 50.3 MB.
//
// conv: 256 thr/block, 16 outputs/thread, one channel/block.
//  - LDS holds only the x window (swizzled, 36.9 KB) -> 4 blocks/CU, 4 waves/SIMD.
//  - Filter read straight from global via block-uniform (scalar) loads.
//  - Window refill: 4x ds_read_b128 per 16-tap phase; 64-reg ring, compile-time slots.

#define LSEQ   4095
#define DMODEL 768
#define KF     4095
#define CROW   4096
#define NCH    1536
#define BL     8190

// alignment-preserving LDS swizzle: +4 pad elements per 32-element block
__device__ __forceinline__ int sw4(int e) { return e + ((e >> 5) << 2); }

// ---------------- embed: x[c=(b,d)][t] = emb[ids[b,t],d] + pos[t,d] ----------
__global__ __launch_bounds__(256)
void embed_kernel(const int* __restrict__ ids, const float* __restrict__ emb,
                  const float* __restrict__ pos, float* __restrict__ xout)
{
    __shared__ float tile[32 * 65];
    const int d0 = blockIdx.x * 64;
    const int t0 = blockIdx.y * 32;
    const int b  = blockIdx.z;
    const int tid = threadIdx.x;

    {   // read phase: coalesced along d
        const int lane = tid & 63, row = tid >> 6;
        #pragma unroll
        for (int r = 0; r < 8; ++r) {
            int tr = row * 8 + r;
            int t  = t0 + tr;
            if (t < LSEQ) {
                int id = ids[b * LSEQ + t];
                tile[tr * 65 + lane] =
                    emb[(size_t)id * DMODEL + d0 + lane] +
                    pos[(size_t)t  * DMODEL + d0 + lane];
            }
        }
    }
    __syncthreads();
    {   // write phase: coalesced along t
        const int lt = tid & 31, drow = tid >> 5;
        #pragma unroll
        for (int r = 0; r < 8; ++r) {
            int dr = drow * 8 + r;
            int t  = t0 + lt;
            if (t < LSEQ)
                xout[(size_t)(b * DMODEL + d0 + dr) * CROW + t] = tile[lt * 65 + dr];
        }
    }
}

// ---------------- one residual long-conv layer --------------------------------
// y[t] = sum_k w[k]*xpad[t+k]; LDS element a lives at lx[sw4(base-ish)]:
// value xpad[j] stored at swizzled index (j+1); reads use e = t + k + 1.
#define PHASE(jj, k0v, NTAPS, DO_REFILL)                                    \
  {                                                                         \
    const int k0 = (k0v);                                                   \
    if (DO_REFILL) {                                                        \
      _Pragma("unroll")                                                     \
      for (int q = 0; q < 4; ++q) {                                         \
        int e0 = base + k0 + 32 + 4 * q;                                    \
        float4 v = *(const float4*)(lx + sw4(e0));                          \
        xw[((jj) * 16 + 31 + 4 * q + 0) & 63] = v.x;                        \
        xw[((jj) * 16 + 31 + 4 * q + 1) & 63] = v.y;                        \
        xw[((jj) * 16 + 31 + 4 * q + 2) & 63] = v.z;                        \
        xw[((jj) * 16 + 31 + 4 * q + 3) & 63] = v.w;                        \
      }                                                                     \
    }                                                                       \
    _Pragma("unroll")                                                       \
    for (int kk = 0; kk < (NTAPS); ++kk) {                                  \
      const float wv = wrow[k0 + kk];   /* block-uniform -> scalar load */  \
      _Pragma("unroll")                                                     \
      for (int o = 0; o < 16; ++o)                                          \
        acc[o] = fmaf(wv, xw[((jj) * 16 + o + kk) & 63], acc[o]);           \
    }                                                                       \
  }

__global__ __launch_bounds__(256, 4)
void conv_kernel(const float* __restrict__ xin, float* __restrict__ xout,
                 const float* __restrict__ w, const float* __restrict__ bias)
{
    __shared__ __align__(16) float lx[9216];   // sw4-swizzled xpad window

    const int c   = blockIdx.x;                // channel 0..1535
    const int du  = __builtin_amdgcn_readfirstlane(c % DMODEL);
    const int tid = threadIdx.x;
    const size_t choff = (size_t)c * CROW;
    const float* __restrict__ wrow = w + (size_t)du * KF;
    const float bv = bias[du];

    // issue global x loads early, zero-fill LDS under their latency
    float4 xv[4];
    const float4* src = (const float4*)(xin + choff);
    #pragma unroll
    for (int r = 0; r < 4; ++r) xv[r] = src[tid + 256 * r];
    for (int i = tid; i < 9216; i += 256) lx[i] = 0.0f;
    __syncthreads();
    #pragma unroll
    for (int r = 0; r < 4; ++r) {
        int e0 = 2048 + 4 * (tid + 256 * r);   // x[t'] at swizzled elem 2048+t'
        *(float4*)(lx + sw4(e0)) = xv[r];
    }
    __syncthreads();

    float acc[16];
    #pragma unroll
    for (int o = 0; o < 16; ++o) acc[o] = 0.0f;

    const int base = tid * 16;                 // e = base + 1 + (k + o)
    float xw[64];                              // ring; slot of element a = a & 63
    #pragma unroll
    for (int m = 0; m < 31; ++m) xw[m] = lx[sw4(base + 1 + m)];

    #pragma unroll 1
    for (int kb = 0; kb < 252; kb += 4) {
        PHASE(0, (kb + 0) * 16, 16, true)
        PHASE(1, (kb + 1) * 16, 16, true)
        PHASE(2, (kb + 2) * 16, 16, true)
        PHASE(3, (kb + 3) * 16, 16, true)
    }
    PHASE(0, 4032, 16, true)
    PHASE(1, 4048, 16, true)
    PHASE(2, 4064, 16, true)      // refill reaches e = base+4111 <= 8191, in-bounds
    PHASE(3, 4080, 15, false)     // taps 4080..4094; k=4095 doesn't exist

    // epilogue: residual + bias
    float vout[16];
    #pragma unroll
    for (int q = 0; q < 4; ++q) {
        int e0 = 2048 + base + 4 * q;
        float4 rv = *(const float4*)(lx + sw4(e0));
        vout[4 * q + 0] = rv.x + acc[4 * q + 0] + bv;
        vout[4 * q + 1] = rv.y + acc[4 * q + 1] + bv;
        vout[4 * q + 2] = rv.z + acc[4 * q + 2] + bv;
        vout[4 * q + 3] = rv.w + acc[4 * q + 3] + bv;
    }
    #pragma unroll
    for (int o = 0; o < 16; ++o)
        if (base + o >= LSEQ) vout[o] = 0.0f;  // keep row element 4095 == 0

    __syncthreads();                           // everyone done reading lx
    #pragma unroll
    for (int q = 0; q < 4; ++q) {              // restage (plain) for coalesced store
        float4 v = { vout[4*q+0], vout[4*q+1], vout[4*q+2], vout[4*q+3] };
        *(float4*)(lx + base + 4 * q) = v;
    }
    __syncthreads();
    float4* dst = (float4*)(xout + choff);
    #pragma unroll
    for (int r = 0; r < 4; ++r) {
        int i = tid + 256 * r;
        dst[i] = *(const float4*)(lx + 4 * i);
    }
}

// ---------------- fused LayerNorm + (D x 2) head ------------------------------
__global__ __launch_bounds__(256)
void head_kernel(const float* __restrict__ x, const float* __restrict__ g,
                 const float* __restrict__ bb, const float* __restrict__ qw,
                 const float* __restrict__ qb, float* __restrict__ out)
{
    const int b = blockIdx.y;
    const int t = blockIdx.x * 256 + threadIdx.x;
    const bool valid = t < LSEQ;
    const int tt = valid ? t : 0;

    float s1 = 0.f, s2 = 0.f, q0 = 0.f, q1 = 0.f;
    float G0 = 0.f, G1 = 0.f, C0 = 0.f, C1 = 0.f;
    const float* xb = x + (size_t)b * DMODEL * CROW + tt;
    for (int dd = 0; dd < DMODEL; ++dd) {
        float xv = xb[(size_t)dd * CROW];
        float gd = g[dd], bd = bb[dd];
        float w0 = qw[2 * dd], w1 = qw[2 * dd + 1];
        s1 += xv;
        s2 = fmaf(xv, xv, s2);
        q0 = fmaf(xv, gd * w0, q0);
        q1 = fmaf(xv, gd * w1, q1);
        G0 = fmaf(gd, w0, G0); G1 = fmaf(gd, w1, G1);
        C0 = fmaf(bd, w0, C0); C1 = fmaf(bd, w1, C1);
    }
    float m   = s1 * (1.0f / 768.0f);
    float var = s2 * (1.0f / 768.0f) - m * m;
    float r   = rsqrtf(var + 1e-5f);
    float l0  = r * (q0 - m * G0) + C0 + qb[0];
    float l1  = r * (q1 - m * G1) + C1 + qb[1];
    if (valid) {
        out[(size_t)b * LSEQ + t] = l0;
        out[BL + (size_t)b * LSEQ + t] = l1;
    }
}

extern "C" void kernel_launch(void* const* d_in, const int* in_sizes, int n_in,
                              void* d_out, int out_size, void* d_ws, size_t ws_size,
                              hipStream_t stream)
{
    const int*   ids = (const int*)  d_in[0];
    const float* emb = (const float*)d_in[1];
    const float* pos = (const float*)d_in[2];
    const float* fw  = (const float*)d_in[3];
    const float* fb  = (const float*)d_in[4];
    const float* lg  = (const float*)d_in[5];
    const float* lb  = (const float*)d_in[6];
    const float* qw  = (const float*)d_in[7];
    const float* qb  = (const float*)d_in[8];
    float* out = (float*)d_out;

    const size_t bufElems = (size_t)NCH * CROW;
    if (ws_size < 2 * bufElems * sizeof(float)) return;

    float* bufA = (float*)d_ws;
    float* bufB = bufA + bufElems;
    // bufA needs element 4095 of each row zeroed (embed writes only t<4095);
    // conv epilogue writes zeros there for every later buffer.
    hipMemsetAsync(bufA, 0, bufElems * sizeof(float), stream);

    embed_kernel<<<dim3(12, 128, 2), 256, 0, stream>>>(ids, emb, pos, bufA);

    const float* cur = bufA;
    float*       nxt = bufB;
    for (int l = 0; l < 12; ++l) {
        conv_kernel<<<NCH, 256, 0, stream>>>(cur, nxt,
                                             fw + (size_t)l * DMODEL * KF,
                                             fb + (size_t)l * DMODEL);
        const float* tmp = nxt;
        nxt = (float*)cur;
        cur = tmp;
    }
    head_kernel<<<dim3(16, 2), 256, 0, stream>>>(cur, lg, lb, qw, qb, out);
}

// Round 4
// 5560.176 us; speedup vs baseline: 1.1021x; 1.0085x over previous
//
#include <hip/hip_runtime.h>

// Hyena QA forward: 12 depthwise long-conv residual layers + LN + 2-logit head.
// Global layout: channel-major tight rows x[c][0..4095], c = b*768 + d,
// signal at [0,4095), element 4095 kept zero. Conv halos exist only in LDS.
// ws: 2 ping-pong buffers = 50.3 MB.
//
// conv: 256 thr/block, 16 outputs/thread, one channel/block.
//  - LDS: x window only, sw (+1/32) swizzle, 33 KB -> 4 blocks/CU.
//  - amdgpu_waves_per_eu(4,4): pin VGPR budget at 128 (R3: compiler went to 64
//    and rematerialized the ring -> +32% VALU + scratch spill).
//  - Ring: 48 regs = 3 chunks x 16, phase p uses chunks p,p+1 (mod 3), refills p+2.
//  - Refill: 16x ds_read_b32 off one base reg (sw is affine within a 16-refill);
//    base regs A0/A1 advance +33 elems every other phase.
//  - Weights: block-uniform scalar (SMEM) loads, no LDS.

#define LSEQ   4095
#define DMODEL 768
#define KF     4095
#define CROW   4096
#define NCH    1536
#define BL     8190

__device__ __forceinline__ int sw(int e) { return e + (e >> 5); }

// ---------------- embed: x[c=(b,d)][t] = emb[ids[b,t],d] + pos[t,d] ----------
__global__ __launch_bounds__(256)
void embed_kernel(const int* __restrict__ ids, const float* __restrict__ emb,
                  const float* __restrict__ pos, float* __restrict__ xout)
{
    __shared__ float tile[32 * 65];
    const int d0 = blockIdx.x * 64;
    const int t0 = blockIdx.y * 32;
    const int b  = blockIdx.z;
    const int tid = threadIdx.x;

    {   // read phase: coalesced along d
        const int lane = tid & 63, row = tid >> 6;
        #pragma unroll
        for (int r = 0; r < 8; ++r) {
            int tr = row * 8 + r;
            int t  = t0 + tr;
            if (t < LSEQ) {
                int id = ids[b * LSEQ + t];
                tile[tr * 65 + lane] =
                    emb[(size_t)id * DMODEL + d0 + lane] +
                    pos[(size_t)t  * DMODEL + d0 + lane];
            }
        }
    }
    __syncthreads();
    {   // write phase: coalesced along t
        const int lt = tid & 31, drow = tid >> 5;
        #pragma unroll
        for (int r = 0; r < 8; ++r) {
            int dr = drow * 8 + r;
            int t  = t0 + lt;
            if (t < LSEQ)
                xout[(size_t)(b * DMODEL + d0 + dr) * CROW + t] = tile[lt * 65 + dr];
        }
    }
}

// ---------------- one residual long-conv layer --------------------------------
// ring slot of conv element (k0 + kk + o): chunk ((p + ((kk+o)>>4)) % 3), slot (kk+o)&15.
// AREG: element index of sw(base + 16p + 32); refill i reads lx[AREG + i].
#define PHASE(PM3, AREG, NTAPS, REFILL)                                       \
  {                                                                           \
    if (REFILL) {                                                             \
      _Pragma("unroll")                                                       \
      for (int i = 0; i < 16; ++i)                                            \
        ring[(((PM3) + 2) % 3) * 16 + i] = lx[(AREG) + i];                    \
      (AREG) += 33;                                                           \
    }                                                                         \
    _Pragma("unroll")                                                         \
    for (int kk = 0; kk < (NTAPS); ++kk) {                                    \
      const float wv = wp[kk];               /* uniform -> s_load */          \
      _Pragma("unroll")                                                       \
      for (int o = 0; o < 16; ++o) {                                          \
        const int r16 = kk + o;                                               \
        acc[o] = fmaf(wv, ring[(((PM3) + (r16 >> 4)) % 3) * 16 + (r16 & 15)], \
                      acc[o]);                                                \
      }                                                                       \
    }                                                                         \
    wp += 16;                                                                 \
  }

__global__ __launch_bounds__(256)
__attribute__((amdgpu_waves_per_eu(4, 4)))
void conv_kernel(const float* __restrict__ xin, float* __restrict__ xout,
                 const float* __restrict__ w, const float* __restrict__ bias)
{
    __shared__ float lx[8448];                 // sw-swizzled xpad[0..8190]

    const int c   = blockIdx.x;                // channel 0..1535
    const int du  = __builtin_amdgcn_readfirstlane(c % DMODEL);
    const int tid = threadIdx.x;
    const size_t choff = (size_t)c * CROW;
    const float* __restrict__ wrow = w + (size_t)du * KF;
    const float bv = bias[du];

    // issue global x loads early, zero-fill LDS under their latency
    float4 xv[4];
    const float4* src = (const float4*)(xin + choff);
    #pragma unroll
    for (int r = 0; r < 4; ++r) xv[r] = src[tid + 256 * r];
    for (int i = tid; i < 8448; i += 256) lx[i] = 0.0f;
    __syncthreads();
    // stage: xpad[j] at lx[sw(j)], xpad[j] = x[j-2047]
    #pragma unroll
    for (int r = 0; r < 4; ++r) {
        int j0 = 2047 + 4 * (tid + 256 * r);
        lx[sw(j0 + 0)] = xv[r].x;
        lx[sw(j0 + 1)] = xv[r].y;
        lx[sw(j0 + 2)] = xv[r].z;
        lx[sw(j0 + 3)] = xv[r].w;
    }
    __syncthreads();

    float acc[16];
    #pragma unroll
    for (int o = 0; o < 16; ++o) acc[o] = 0.0f;

    const int base = tid * 16;                 // conv element e = base + k + o
    float ring[48];                            // 3 chunks x 16
    {   // prefill chunks 0 (elems base+0..15) and 1 (base+16..31)
        int Ai0 = sw(base), Ai1 = sw(base + 16);
        #pragma unroll
        for (int i = 0; i < 16; ++i) ring[i]      = lx[Ai0 + i];
        #pragma unroll
        for (int i = 0; i < 16; ++i) ring[16 + i] = lx[Ai1 + i];
    }
    int A0 = sw(base + 32);                    // even-phase refill base
    int A1 = sw(base + 48);                    // odd-phase refill base
    const float* wp = wrow;

    #pragma unroll 1
    for (int g = 0; g < 42; ++g) {             // phases 6g .. 6g+5
        PHASE(0, A0, 16, true)                 // p%6=0 (even)
        PHASE(1, A1, 16, true)                 // p%6=1 (odd)
        PHASE(2, A0, 16, true)
        PHASE(0, A1, 16, true)
        PHASE(1, A0, 16, true)
        PHASE(2, A1, 16, true)
    }
    PHASE(0, A0, 16, true)                     // p=252
    PHASE(1, A1, 16, true)                     // p=253
    PHASE(2, A0, 16, true)                     // p=254 (reads zeros at edge)
    PHASE(0, A1, 15, false)                    // p=255: taps 4080..4094

    // epilogue: residual + bias
    float vout[16];
    #pragma unroll
    for (int o = 0; o < 16; ++o) {
        int t = base + o;
        float xr = lx[sw(2047 + t)];
        vout[o] = (t < LSEQ) ? (xr + acc[o] + bv) : 0.0f;
    }
    __syncthreads();                           // all reads of lx done
    #pragma unroll
    for (int o = 0; o < 16; ++o) lx[base + o] = vout[o];   // plain restage
    __syncthreads();
    float4* dst = (float4*)(xout + choff);
    #pragma unroll
    for (int r = 0; r < 4; ++r) {
        int i = tid + 256 * r;
        dst[i] = *(const float4*)(lx + 4 * i);
    }
}

// ---------------- fused LayerNorm + (D x 2) head ------------------------------
__global__ __launch_bounds__(256)
void head_kernel(const float* __restrict__ x, const float* __restrict__ g,
                 const float* __restrict__ bb, const float* __restrict__ qw,
                 const float* __restrict__ qb, float* __restrict__ out)
{
    const int b = blockIdx.y;
    const int t = blockIdx.x * 256 + threadIdx.x;
    const bool valid = t < LSEQ;
    const int tt = valid ? t : 0;

    float s1 = 0.f, s2 = 0.f, q0 = 0.f, q1 = 0.f;
    float G0 = 0.f, G1 = 0.f, C0 = 0.f, C1 = 0.f;
    const float* xb = x + (size_t)b * DMODEL * CROW + tt;
    for (int dd = 0; dd < DMODEL; ++dd) {
        float xv = xb[(size_t)dd * CROW];
        float gd = g[dd], bd = bb[dd];
        float w0 = qw[2 * dd], w1 = qw[2 * dd + 1];
        s1 += xv;
        s2 = fmaf(xv, xv, s2);
        q0 = fmaf(xv, gd * w0, q0);
        q1 = fmaf(xv, gd * w1, q1);
        G0 = fmaf(gd, w0, G0); G1 = fmaf(gd, w1, G1);
        C0 = fmaf(bd, w0, C0); C1 = fmaf(bd, w1, C1);
    }
    float m   = s1 * (1.0f / 768.0f);
    float var = s2 * (1.0f / 768.0f) - m * m;
    float r   = rsqrtf(var + 1e-5f);
    float l0  = r * (q0 - m * G0) + C0 + qb[0];
    float l1  = r * (q1 - m * G1) + C1 + qb[1];
    if (valid) {
        out[(size_t)b * LSEQ + t] = l0;
        out[BL + (size_t)b * LSEQ + t] = l1;
    }
}

extern "C" void kernel_launch(void* const* d_in, const int* in_sizes, int n_in,
                              void* d_out, int out_size, void* d_ws, size_t ws_size,
                              hipStream_t stream)
{
    const int*   ids = (const int*)  d_in[0];
    const float* emb = (const float*)d_in[1];
    const float* pos = (const float*)d_in[2];
    const float* fw  = (const float*)d_in[3];
    const float* fb  = (const float*)d_in[4];
    const float* lg  = (const float*)d_in[5];
    const float* lb  = (const float*)d_in[6];
    const float* qw  = (const float*)d_in[7];
    const float* qb  = (const float*)d_in[8];
    float* out = (float*)d_out;

    const size_t bufElems = (size_t)NCH * CROW;
    if (ws_size < 2 * bufElems * sizeof(float)) return;

    float* bufA = (float*)d_ws;
    float* bufB = bufA + bufElems;
    // bufA row element 4095 must be 0 (embed writes only t<4095);
    // conv epilogue writes zeros there for all later buffers.
    hipMemsetAsync(bufA, 0, bufElems * sizeof(float), stream);

    embed_kernel<<<dim3(12, 128, 2), 256, 0, stream>>>(ids, emb, pos, bufA);

    const float* cur = bufA;
    float*       nxt = bufB;
    for (int l = 0; l < 12; ++l) {
        conv_kernel<<<NCH, 256, 0, stream>>>(cur, nxt,
                                             fw + (size_t)l * DMODEL * KF,
                                             fb + (size_t)l * DMODEL);
        const float* tmp = nxt;
        nxt = (float*)cur;
        cur = tmp;
    }
    head_kernel<<<dim3(16, 2), 256, 0, stream>>>(cur, lg, lb, qw, qb, out);
}